// Round 10
// baseline (615.253 us; speedup 1.0000x reference)
//
#include <hip/hip_runtime.h>
#include <hip/hip_bf16.h>
#include <cstdint>
#include <type_traits>

// LocalRNN: B=16 L=1024 D=256 H=256 K=16 (GRU over K-window per position).
// FP32 in/out. Round-10 = r7 (proven 141us: 512thr/8 waves, 32-col stripes,
// wf=192 regs/wave at 2 waves/SIMD, fused gi GEMM, exp2-folded gates) plus:
//   * 2-bank software pipeline: mfma(sub s+1) issued before gates(sub s) so
//     gate VALU runs in the shadow of independent MFMAs.
//   * wave-parity stagger (waves 4-7 start at sub 2, compile-time branch) so
//     half the waves are in MFMA phase while half are in gate phase.
//   * h-old read from LDS (hreg dropped; frees 16 regs for the 2nd acc bank).
// r8/r9 lesson: 16-wave/16-col + 96-reg wf can't fit a 128-reg budget; the
// compiler spills wf to scratch (FETCH 123MB). Stay at (512,2).

#define B_  16
#define L_  1024
#define D_  256
#define H_  256
#define K_  16
#define MT  32             // positions per block
#define NROW 47            // gi rows per block = MT + K - 1
#define HS  264            // h/xs LDS row stride (u16)
#define GRS 258            // grz LDS row stride (u32)
#define GNS 264            // gn LDS row stride (u16)
#define L2E 1.44269504f
#define NWR 196608         // 768*256

typedef __attribute__((ext_vector_type(8))) short  bf16x8;
typedef __attribute__((ext_vector_type(4))) float  floatx4;
typedef unsigned short ush;

#if __has_builtin(__builtin_amdgcn_exp2f)
#define fexp2(x) __builtin_amdgcn_exp2f(x)
#else
#define fexp2(x) exp2f(x)
#endif

__device__ __forceinline__ float bf2f(ush u) {
    union { unsigned int i; float f; } v; v.i = ((unsigned int)u) << 16; return v.f;
}
__device__ __forceinline__ ush f2bf(float f) {
    union { float f; unsigned int i; } v; v.f = f;
    unsigned int x = v.i;
    return (ush)((x + 0x7FFFu + ((x >> 16) & 1u)) >> 16);  // RNE
}
__device__ __forceinline__ unsigned int pk2(float a, float b) {
    union { __hip_bfloat162 v; unsigned int u; } c;
    c.v = __float22bfloat162_rn(make_float2(a, b));  // lo=a, hi=b
    return c.u;
}
__device__ __forceinline__ float rcpf(float x) { return __builtin_amdgcn_rcpf(x); }

template <int N> using ic = std::integral_constant<int, N>;

// ---- wprep: repack W_ih and W_hh into per-wave frag layout, scale-folded ---
// frag n = gate*2 + sloc; e = ((w*6 + n)*8 + ks)*512 + lane*8 + j (w = wave 0..7)
__global__ __launch_bounds__(256) void wprep(const float* __restrict__ Wih,
                                             const float* __restrict__ Whh,
                                             ush* __restrict__ Wir,
                                             ush* __restrict__ Wr) {
    int idx = blockIdx.x * 256 + threadIdx.x;
    const float* src = (idx < NWR) ? Whh : Wih;
    ush* dst         = (idx < NWR) ? Wr  : Wir;
    int e = (idx < NWR) ? idx : idx - NWR;
    int w    = e / 24576, r1 = e % 24576;   // wave
    int n    = r1 / 4096,  r2 = r1 % 4096;  // frag = gate*2 + sloc
    int ks   = r2 / 512,   r3 = r2 % 512;
    int lane = r3 >> 3,    j  = r3 & 7;
    int l16 = lane & 15, quad = lane >> 4;
    int gate = n >> 1, sloc = n & 1;
    int srow = gate * 256 + (2 * w + sloc) * 16 + l16;
    int scol = ks * 32 + quad * 8 + j;
    float scl = (gate < 2) ? -L2E : 2.f * L2E;
    dst[e] = f2bf(src[srow * 256 + scol] * scl);
}

// ---- fused kernel: 512 blocks x 512 thr, 2 waves/SIMD ----------------------
__global__ __launch_bounds__(512, 2) void rnn_fused(const float* __restrict__ x,
                                                    const ush* __restrict__ Wir,
                                                    const ush* __restrict__ Wr,
                                                    const float* __restrict__ bih,
                                                    const float* __restrict__ bhh,
                                                    float* __restrict__ out) {
    __shared__ __align__(16) ush xs[48 * HS];       // 25,344 B  staged x (bf16)
    __shared__ unsigned int grz[NROW * GRS];        // 48,504 B
    __shared__ __align__(16) ush gn[NROW * GNS];    // 24,816 B
    __shared__ __align__(16) ush hl[2][MT * HS];    // 33,792 B  (tot 132,456)

    int tid  = threadIdx.x;
    int wave = tid >> 6, lane = tid & 63;
    int l16  = lane & 15, quad = lane >> 4, quad4 = quad * 4;
    int p0   = blockIdx.x * MT;
    int bb   = p0 >> 10, lb = p0 & 1023;
    int base = wave * 32 + l16;               // thread's first hidden col

    // ---- stage x rows j=0..47 (token lb-15+j, zero-padded) + zero h[0] -----
    {
        const float4* x4 = (const float4*)x;
        for (int idx = tid; idx < 48 * 64; idx += 512) {
            int j = idx >> 6, c = idx & 63;
            int tok = lb - 15 + j;
            float4 v = make_float4(0.f, 0.f, 0.f, 0.f);
            if (tok >= 0 && tok < L_) v = x4[(size_t)((bb << 10) + tok) * 64 + c];
            *(uint2*)(xs + j * HS + c * 4) = make_uint2(pk2(v.x, v.y), pk2(v.z, v.w));
        }
        for (int idx = tid; idx < MT * HS / 2; idx += 512)
            ((unsigned int*)(&hl[0][0]))[idx] = 0u;
    }
    __syncthreads();

    // ---- in-block gi GEMM: 48 rows x (6 col-frags for this wave) -----------
    {
        floatx4 gacc[3][6];  // [m-tile][frag = gate*2 + sl]
#pragma unroll
        for (int sl = 0; sl < 2; sl++) {
            int cs = base + sl * 16;
            float ir = -L2E * (bih[cs] + bhh[cs]);
            float iz = -L2E * (bih[256 + cs] + bhh[256 + cs]);
            float in_ = 2.f * L2E * bih[512 + cs];
#pragma unroll
            for (int mt = 0; mt < 3; mt++) {
                gacc[mt][0 + sl] = (floatx4){ir, ir, ir, ir};
                gacc[mt][2 + sl] = (floatx4){iz, iz, iz, iz};
                gacc[mt][4 + sl] = (floatx4){in_, in_, in_, in_};
            }
        }
        const ush* wp = Wir + (size_t)wave * 24576 + lane * 8;
#pragma unroll
        for (int ks = 0; ks < 8; ks++) {
            bf16x8 bw[6];
#pragma unroll
            for (int n = 0; n < 6; n++)
                bw[n] = *(const bf16x8*)(wp + ((n * 8 + ks) << 9));
#pragma unroll
            for (int mt = 0; mt < 3; mt++) {
                bf16x8 af = *(const bf16x8*)(xs + (mt * 16 + l16) * HS + ks * 32 + quad * 8);
#pragma unroll
                for (int n = 0; n < 6; n++)
                    gacc[mt][n] = __builtin_amdgcn_mfma_f32_16x16x32_bf16(
                        af, bw[n], gacc[mt][n], 0, 0, 0);
            }
        }
        // pack into grz/gn (C/D: col=l16 -> cs, row=quad4+r -> window row)
#pragma unroll
        for (int mt = 0; mt < 3; mt++)
#pragma unroll
            for (int sl = 0; sl < 2; sl++) {
                int cs = base + sl * 16;
#pragma unroll
                for (int r = 0; r < 4; r++) {
                    int j = mt * 16 + quad4 + r;
                    if (j < NROW) {
                        grz[j * GRS + cs] = pk2(gacc[mt][0 + sl][r], gacc[mt][2 + sl][r]);
                        gn[j * GNS + cs]  = f2bf(gacc[mt][4 + sl][r]);
                    }
                }
            }
    }

    // ---- W_hh fragments (scaled) -> 192 regs, held across all 16 steps -----
    bf16x8 wf[6][8];
    {
        const ush* wp = Wr + (size_t)wave * 24576 + lane * 8;
#pragma unroll
        for (int n = 0; n < 6; n++)
#pragma unroll
            for (int ks = 0; ks < 8; ks++)
                wf[n][ks] = *(const bf16x8*)(wp + ((n * 8 + ks) << 9));
    }
    float bn0 = 2.f * L2E * bhh[512 + base];
    float bn1 = 2.f * L2E * bhh[512 + base + 16];
    __syncthreads();  // gi writes + h[0] zero visible

    // ---- GRU loop: 2-bank pipelined sub-steps, parity-staggered ------------
    for (int t = 0; t < K_; t++) {
        const ush* hc = &hl[t & 1][0];
        ush*       hx = &hl[(t + 1) & 1][0];

        floatx4      A[2][3];
        unsigned int C[2][4];

        // sub = T*2 + sl (T: position half, sl: col stripe)
        auto mfma_sub = [&](auto subc, auto bankc) {
            constexpr int sub = decltype(subc)::value;
            constexpr int bk  = decltype(bankc)::value;
            constexpr int T = sub >> 1, sl = sub & 1;
            int colx = base + sl * 16;
            int r0 = T * 16 + quad4 + t;
            C[bk][0] = grz[(r0 + 0) * GRS + colx];
            C[bk][1] = grz[(r0 + 1) * GRS + colx];
            C[bk][2] = grz[(r0 + 2) * GRS + colx];
            C[bk][3] = grz[(r0 + 3) * GRS + colx];
            float bnv = sl ? bn1 : bn0;
            A[bk][0] = (floatx4){0.f, 0.f, 0.f, 0.f};
            A[bk][1] = (floatx4){0.f, 0.f, 0.f, 0.f};
            A[bk][2] = (floatx4){bnv, bnv, bnv, bnv};
            const ush* ha = hc + (T * 16 + l16) * HS + quad * 8;
#pragma unroll
            for (int ks = 0; ks < 8; ks++) {
                bf16x8 af = *(const bf16x8*)(ha + ks * 32);
                A[bk][0] = __builtin_amdgcn_mfma_f32_16x16x32_bf16(af, wf[0 + sl][ks], A[bk][0], 0, 0, 0);
                A[bk][1] = __builtin_amdgcn_mfma_f32_16x16x32_bf16(af, wf[2 + sl][ks], A[bk][1], 0, 0, 0);
                A[bk][2] = __builtin_amdgcn_mfma_f32_16x16x32_bf16(af, wf[4 + sl][ks], A[bk][2], 0, 0, 0);
            }
        };
        auto gates_sub = [&](auto subc, auto bankc) {
            constexpr int sub = decltype(subc)::value;
            constexpr int bk  = decltype(bankc)::value;
            constexpr int T = sub >> 1, sl = sub & 1;
            int colx = base + sl * 16;
            int r0 = T * 16 + quad4 + t;
            int hb = (T * 16 + quad4) * HS + colx;
#pragma unroll
            for (int r = 0; r < 4; r++) {
                unsigned int c = C[bk][r];
                float gv = bf2f(gn[(r0 + r) * GNS + colx]);
                float ar = A[bk][0][r] + __uint_as_float(c << 16);
                float az = A[bk][1][r] + __uint_as_float(c & 0xffff0000u);
                float rg = rcpf(1.f + fexp2(ar));            // sigmoid(-scaled)
                float zg = rcpf(1.f + fexp2(az));
                float u  = gv + rg * A[bk][2][r];
                float ng = 1.f - 2.f * rcpf(fexp2(u) + 1.f); // tanh(2log2e-scaled)
                float ho = bf2f(hc[hb + r * HS]);
                hx[hb + r * HS] = f2bf(ng + zg * (ho - ng));
            }
        };
        auto run4 = [&](auto sa, auto sb, auto sc, auto sd) {
            mfma_sub(sa, ic<0>{});
            mfma_sub(sb, ic<1>{});
            gates_sub(sa, ic<0>{});   // VALU overlaps MFMAs of sb already issued
            mfma_sub(sc, ic<0>{});
            gates_sub(sb, ic<1>{});
            mfma_sub(sd, ic<1>{});
            gates_sub(sc, ic<0>{});
            gates_sub(sd, ic<1>{});
        };
        if (wave & 4) run4(ic<2>{}, ic<3>{}, ic<0>{}, ic<1>{});
        else          run4(ic<0>{}, ic<1>{}, ic<2>{}, ic<3>{});
        __syncthreads();
    }

    // ---- final h (in hl[0]) -> out (fp32), own cells -----------------------
#pragma unroll
    for (int T = 0; T < 2; T++)
#pragma unroll
        for (int sl = 0; sl < 2; sl++)
#pragma unroll
            for (int r = 0; r < 4; r++) {
                int row = T * 16 + quad4 + r, col = base + sl * 16;
                out[(size_t)(p0 + row) * H_ + col] = bf2f(hl[0][row * HS + col]);
            }
}

extern "C" void kernel_launch(void* const* d_in, const int* in_sizes, int n_in,
                              void* d_out, int out_size, void* d_ws, size_t ws_size,
                              hipStream_t stream) {
    const float* x    = (const float*)d_in[0];
    const float* W_ih = (const float*)d_in[1];
    const float* W_hh = (const float*)d_in[2];
    const float* b_ih = (const float*)d_in[3];
    const float* b_hh = (const float*)d_in[4];
    float* out = (float*)d_out;

    // ws layout (bytes): Wir 393,216 | Wr 393,216  (scaled, wave-blocked)
    char* ws = (char*)d_ws;
    ush* Wir = (ush*)ws;
    ush* Wr  = (ush*)(ws + 393216);

    wprep<<<2 * NWR / 256, 256, 0, stream>>>(W_ih, W_hh, Wir, Wr);
    rnn_fused<<<B_ * L_ / MT, 512, 0, stream>>>(x, Wir, Wr, b_ih, b_hh, out);
}

// Round 11
// 189.696 us; speedup vs baseline: 3.2434x; 3.2434x over previous
//
#include <hip/hip_runtime.h>
#include <hip/hip_bf16.h>
#include <cstdint>

// LocalRNN: B=16 L=1024 D=256 H=256 K=16 (GRU over K-window per position).
// FP32 in/out. Round-11 = r7's rnn_fused EXACTLY (141us, proven: 512thr/8
// waves, 32-col stripes, wf=192 regs/wave at 2 waves/SIMD = the 256-unified-
// reg cliff; do NOT add registers to the GRU loop) + source-coalesced wprep
// (r7's wprep gathered 1 fp32/thread with 256-float row jumps; now each
// thread reads 32B contiguous and writes 16B contiguous frag chunks).
// Register-cliff ledger (r8/r9/r10 post-mortems): (512,2) gives 256 unified
// regs/wave; wf=192 (128 AGPR + 64 VGPR) + ~64 VGPR temps = exactly 256.
// +12 regs (r10 A-banks) => wf spills to scratch, FETCH 15MB -> 1.7GB.

#define B_  16
#define L_  1024
#define D_  256
#define H_  256
#define K_  16
#define MT  32             // positions per block
#define NROW 47            // gi rows per block = MT + K - 1
#define HS  264            // h/xs LDS row stride (u16)
#define GRS 258            // grz LDS row stride (u32)
#define GNS 264            // gn LDS row stride (u16)
#define L2E 1.44269504f
#define NWR 196608         // 768*256

typedef __attribute__((ext_vector_type(8))) short  bf16x8;
typedef __attribute__((ext_vector_type(4))) float  floatx4;
typedef unsigned short ush;

#if __has_builtin(__builtin_amdgcn_exp2f)
#define fexp2(x) __builtin_amdgcn_exp2f(x)
#else
#define fexp2(x) exp2f(x)
#endif

__device__ __forceinline__ float bf2f(ush u) {
    union { unsigned int i; float f; } v; v.i = ((unsigned int)u) << 16; return v.f;
}
__device__ __forceinline__ ush f2bf(float f) {
    union { float f; unsigned int i; } v; v.f = f;
    unsigned int x = v.i;
    return (ush)((x + 0x7FFFu + ((x >> 16) & 1u)) >> 16);  // RNE
}
__device__ __forceinline__ unsigned int pk2(float a, float b) {
    union { __hip_bfloat162 v; unsigned int u; } c;
    c.v = __float22bfloat162_rn(make_float2(a, b));  // lo=a, hi=b
    return c.u;
}
__device__ __forceinline__ float rcpf(float x) { return __builtin_amdgcn_rcpf(x); }

// ---- wprep (coalesced): thread = 8-elem chunk of one weight row ------------
// dst frag layout (per r7): e = ((w*6 + gate*2 + sloc)*8 + ks)*512 + lane*8 + j
// srow = gate*256 + (2w+sloc)*16 + l16, scol = ks*32 + quad*8 + j,
// lane = quad*16 + l16.  For a chunk (srow, scol0=ch*8): j=0..7 are contiguous
// in BOTH src (32B fp32) and dst (16B bf16).
#define NCHUNK 24576   // 768 rows * 32 chunks, per matrix
__global__ __launch_bounds__(256) void wprep(const float* __restrict__ Wih,
                                             const float* __restrict__ Whh,
                                             ush* __restrict__ Wir,
                                             ush* __restrict__ Wr) {
    int idx = blockIdx.x * 256 + threadIdx.x;      // 0 .. 2*NCHUNK-1
    const float* src = (idx < NCHUNK) ? Whh : Wih;
    ush* dst         = (idx < NCHUNK) ? Wr  : Wir;
    int c = (idx < NCHUNK) ? idx : idx - NCHUNK;
    int srow = c >> 5, ch = c & 31;
    int gate = srow >> 8, rr = srow & 255;
    int w    = rr >> 5;
    int sloc = (rr >> 4) & 1;
    int l16  = rr & 15;
    int ks   = ch >> 2;          // scol0 = ch*8 -> ks = scol0/32
    int quad = ch & 3;           // (scol0 & 31) / 8
    int lane = quad * 16 + l16;
    int e0 = (((w * 6 + gate * 2 + sloc) * 8 + ks) << 9) + lane * 8;
    float scl = (gate < 2) ? -L2E : 2.f * L2E;
    const float* s = src + srow * 256 + ch * 8;
    float4 v0 = *(const float4*)(s);
    float4 v1 = *(const float4*)(s + 4);
    *(uint4*)(dst + e0) = make_uint4(pk2(v0.x * scl, v0.y * scl),
                                     pk2(v0.z * scl, v0.w * scl),
                                     pk2(v1.x * scl, v1.y * scl),
                                     pk2(v1.z * scl, v1.w * scl));
}

// ---- fused kernel (byte-identical to r7's 141us version) -------------------
__global__ __launch_bounds__(512, 2) void rnn_fused(const float* __restrict__ x,
                                                    const ush* __restrict__ Wir,
                                                    const ush* __restrict__ Wr,
                                                    const float* __restrict__ bih,
                                                    const float* __restrict__ bhh,
                                                    float* __restrict__ out) {
    __shared__ __align__(16) ush xs[48 * HS];       // 25,344 B  staged x (bf16)
    __shared__ unsigned int grz[NROW * GRS];        // 48,504 B
    __shared__ __align__(16) ush gn[NROW * GNS];    // 24,816 B
    __shared__ __align__(16) ush hl[2][MT * HS];    // 33,792 B  (tot 132,456)

    int tid  = threadIdx.x;
    int wave = tid >> 6, lane = tid & 63;
    int l16  = lane & 15, quad = lane >> 4, quad4 = quad * 4;
    int p0   = blockIdx.x * MT;
    int bb   = p0 >> 10, lb = p0 & 1023;
    int base = wave * 32 + l16;               // thread's first hidden col

    // ---- stage x rows j=0..47 (token lb-15+j, zero-padded) + zero h[0] -----
    {
        const float4* x4 = (const float4*)x;
        for (int idx = tid; idx < 48 * 64; idx += 512) {
            int j = idx >> 6, c = idx & 63;
            int tok = lb - 15 + j;
            float4 v = make_float4(0.f, 0.f, 0.f, 0.f);
            if (tok >= 0 && tok < L_) v = x4[(size_t)((bb << 10) + tok) * 64 + c];
            *(uint2*)(xs + j * HS + c * 4) = make_uint2(pk2(v.x, v.y), pk2(v.z, v.w));
        }
        for (int idx = tid; idx < MT * HS / 2; idx += 512)
            ((unsigned int*)(&hl[0][0]))[idx] = 0u;
    }
    __syncthreads();

    // ---- in-block gi GEMM: 48 rows x (6 col-frags for this wave) -----------
    {
        floatx4 gacc[3][6];  // [m-tile][frag = gate*2 + sl]
#pragma unroll
        for (int sl = 0; sl < 2; sl++) {
            int cs = base + sl * 16;
            float ir = -L2E * (bih[cs] + bhh[cs]);
            float iz = -L2E * (bih[256 + cs] + bhh[256 + cs]);
            float in_ = 2.f * L2E * bih[512 + cs];
#pragma unroll
            for (int mt = 0; mt < 3; mt++) {
                gacc[mt][0 + sl] = (floatx4){ir, ir, ir, ir};
                gacc[mt][2 + sl] = (floatx4){iz, iz, iz, iz};
                gacc[mt][4 + sl] = (floatx4){in_, in_, in_, in_};
            }
        }
        const ush* wp = Wir + (size_t)wave * 24576 + lane * 8;
#pragma unroll
        for (int ks = 0; ks < 8; ks++) {
            bf16x8 bw[6];
#pragma unroll
            for (int n = 0; n < 6; n++)
                bw[n] = *(const bf16x8*)(wp + ((n * 8 + ks) << 9));
#pragma unroll
            for (int mt = 0; mt < 3; mt++) {
                bf16x8 af = *(const bf16x8*)(xs + (mt * 16 + l16) * HS + ks * 32 + quad * 8);
#pragma unroll
                for (int n = 0; n < 6; n++)
                    gacc[mt][n] = __builtin_amdgcn_mfma_f32_16x16x32_bf16(
                        af, bw[n], gacc[mt][n], 0, 0, 0);
            }
        }
        // pack into grz/gn (C/D: col=l16 -> cs, row=quad4+r -> window row)
#pragma unroll
        for (int mt = 0; mt < 3; mt++)
#pragma unroll
            for (int sl = 0; sl < 2; sl++) {
                int cs = base + sl * 16;
#pragma unroll
                for (int r = 0; r < 4; r++) {
                    int j = mt * 16 + quad4 + r;
                    if (j < NROW) {
                        grz[j * GRS + cs] = pk2(gacc[mt][0 + sl][r], gacc[mt][2 + sl][r]);
                        gn[j * GNS + cs]  = f2bf(gacc[mt][4 + sl][r]);
                    }
                }
            }
    }

    // ---- W_hh fragments (scaled) -> 192 regs, held across all 16 steps -----
    bf16x8 wf[6][8];
    {
        const ush* wp = Wr + (size_t)wave * 24576 + lane * 8;
#pragma unroll
        for (int n = 0; n < 6; n++)
#pragma unroll
            for (int ks = 0; ks < 8; ks++)
                wf[n][ks] = *(const bf16x8*)(wp + ((n * 8 + ks) << 9));
    }
    float bn0 = 2.f * L2E * bhh[512 + base];
    float bn1 = 2.f * L2E * bhh[512 + base + 16];
    float hreg[16];
#pragma unroll
    for (int q = 0; q < 16; q++) hreg[q] = 0.f;
    __syncthreads();  // gi writes + h[0] zero visible

    // ---- GRU loop: one barrier per step ------------------------------------
    for (int t = 0; t < K_; t++) {
        const ush* hc  = &hl[t & 1][0];
        ush*       hnx = &hl[(t + 1) & 1][0];
#pragma unroll
        for (int T = 0; T < 2; T++) {
#pragma unroll
            for (int sl = 0; sl < 2; sl++) {
                int col = base + sl * 16;
                int r0  = T * 16 + quad4 + t;
                unsigned int c0 = grz[(r0 + 0) * GRS + col];
                unsigned int c1 = grz[(r0 + 1) * GRS + col];
                unsigned int c2 = grz[(r0 + 2) * GRS + col];
                unsigned int c3 = grz[(r0 + 3) * GRS + col];
                float bn = sl ? bn1 : bn0;
                floatx4 a0 = (floatx4){0.f, 0.f, 0.f, 0.f};
                floatx4 a1 = (floatx4){0.f, 0.f, 0.f, 0.f};
                floatx4 a2 = (floatx4){bn, bn, bn, bn};
                const ush* ha = hc + (T * 16 + l16) * HS + quad * 8;
#pragma unroll
                for (int ks = 0; ks < 8; ks++) {
                    bf16x8 af = *(const bf16x8*)(ha + ks * 32);
                    a0 = __builtin_amdgcn_mfma_f32_16x16x32_bf16(af, wf[0 + sl][ks], a0, 0, 0, 0);
                    a1 = __builtin_amdgcn_mfma_f32_16x16x32_bf16(af, wf[2 + sl][ks], a1, 0, 0, 0);
                    a2 = __builtin_amdgcn_mfma_f32_16x16x32_bf16(af, wf[4 + sl][ks], a2, 0, 0, 0);
                }
                unsigned int cc[4] = {c0, c1, c2, c3};
                int hb = (T * 16 + quad4) * HS + col;
#pragma unroll
                for (int r = 0; r < 4; r++) {
                    float ar = a0[r] + __uint_as_float(cc[r] << 16);
                    float az = a1[r] + __uint_as_float(cc[r] & 0xffff0000u);
                    float rg = rcpf(1.f + fexp2(ar));   // sigmoid (pre-scaled -log2e)
                    float zg = rcpf(1.f + fexp2(az));
                    float u  = bf2f(gn[(r0 + r) * GNS + col]) + rg * a2[r];
                    float ng = 1.f - 2.f * rcpf(fexp2(u) + 1.f);  // tanh (pre-scaled)
                    int q = T * 8 + sl * 4 + r;
                    float hv = ng + zg * (hreg[q] - ng);
                    hreg[q] = hv;
                    hnx[hb + r * HS] = f2bf(hv);
                }
            }
        }
        __syncthreads();
    }
    // ---- final h -> out (fp32), own cells ----------------------------------
#pragma unroll
    for (int T = 0; T < 2; T++)
#pragma unroll
        for (int sl = 0; sl < 2; sl++)
#pragma unroll
            for (int r = 0; r < 4; r++) {
                int row = T * 16 + quad4 + r, col = base + sl * 16;
                out[(size_t)(p0 + row) * H_ + col] = hreg[T * 8 + sl * 4 + r];
            }
}

extern "C" void kernel_launch(void* const* d_in, const int* in_sizes, int n_in,
                              void* d_out, int out_size, void* d_ws, size_t ws_size,
                              hipStream_t stream) {
    const float* x    = (const float*)d_in[0];
    const float* W_ih = (const float*)d_in[1];
    const float* W_hh = (const float*)d_in[2];
    const float* b_ih = (const float*)d_in[3];
    const float* b_hh = (const float*)d_in[4];
    float* out = (float*)d_out;

    // ws layout (bytes): Wir 393,216 | Wr 393,216  (scaled, wave-blocked)
    char* ws = (char*)d_ws;
    ush* Wir = (ush*)ws;
    ush* Wr  = (ush*)(ws + 393216);

    wprep<<<2 * NCHUNK / 256, 256, 0, stream>>>(W_ih, W_hh, Wir, Wr);
    rnn_fused<<<B_ * L_ / MT, 512, 0, stream>>>(x, Wir, Wr, b_ih, b_hh, out);
}